// Round 1
// baseline (2060.427 us; speedup 1.0000x reference)
//
#include <hip/hip_runtime.h>
#include <math.h>

typedef unsigned long long u64;
typedef unsigned int u32;

#define B_ 4
#define N_ 8192
#define K_ 16
#define W0_ 64
#define W1_ 128
#define W2_ 256
#define P_ 8   // points per block in head kernel

// ---------------- prep: coords4 (x,y,z_eff,xx) + stem MLP ----------------
__global__ __launch_bounds__(64) void prep_kernel(
    const float* __restrict__ x,
    const float* __restrict__ stem_w, const float* __restrict__ stem_b,
    const float* __restrict__ hmix_a, const float* __restrict__ hmix_b,
    const float* __restrict__ hmix_c,
    float* __restrict__ coords4, float* __restrict__ f0) {
  const int p = blockIdx.x;          // global point 0..B*N-1
  const int o = threadIdx.x;         // 0..63
  const float x0 = x[p*4+0], x1 = x[p*4+1], x2 = x[p*4+2], x3 = x[p*4+3];
  float acc = stem_b[o];
  acc += x0*stem_w[0*W0_+o];
  acc += x1*stem_w[1*W0_+o];
  acc += x2*stem_w[2*W0_+o];
  acc += x3*stem_w[3*W0_+o];
  f0[p*W0_+o] = fmaxf(acc, 0.f);
  if (o == 0) {
    const float z  = hmix_a[0]*x2 + hmix_b[0]*x3 + hmix_c[0];
    const float xx = x0*x0 + x1*x1 + z*z;
    ((float4*)coords4)[p] = make_float4(x0, x1, z, xx);
  }
}

// ---------------- knn: one wave per point, exact top-16 by (dist, idx) ----------------
__global__ __launch_bounds__(64) void knn_kernel(
    const float* __restrict__ coords4, int* __restrict__ knn_idx) {
  const int p = blockIdx.x;
  const int b = p >> 13;             // /8192
  const int lane = threadIdx.x;
  const float4* cb = ((const float4*)coords4) + (b << 13);
  const float4 ci = ((const float4*)coords4)[p];

  u64 arr[K_];
#pragma unroll
  for (int t = 0; t < K_; ++t) arr[t] = ~0ull;

  for (int it = 0; it < N_/64; ++it) {
    const int j = lane + it*64;
    const float4 cj = cb[j];
    const float dot = ci.x*cj.x + ci.y*cj.y + ci.z*cj.z;
    float d = ci.w + cj.w - 2.f*dot;
    d = fmaxf(d, 0.f);
    u64 key = ((u64)__float_as_uint(d) << 32) | (u32)j;
    // sorted-ascending insertion sweep (registers only, fully unrolled)
#pragma unroll
    for (int t = 0; t < K_; ++t) {
      const bool lt = key < arr[t];
      const u64 lo = lt ? key : arr[t];
      const u64 hi = lt ? arr[t] : key;
      arr[t] = lo;
      key = hi;
    }
  }
  // merge 64 sorted lists -> global top-16 via 16 rounds of wave-min + pop
  const int base = p * K_;
  for (int r = 0; r < K_; ++r) {
    u64 m = arr[0];
#pragma unroll
    for (int s = 32; s > 0; s >>= 1) {
      const u64 oth = __shfl_xor(m, s, 64);
      m = (oth < m) ? oth : m;
    }
    const bool own = (arr[0] == m);   // keys unique (idx embedded) -> exactly one owner
#pragma unroll
    for (int t = 0; t < K_-1; ++t) arr[t] = own ? arr[t+1] : arr[t];
    arr[K_-1] = own ? ~0ull : arr[K_-1];
    if (lane == 0) knn_idx[base + r] = (int)(u32)(m & 0xffffffffull);
  }
}

// ---------------- local_agg: relu(concat[fi, nb-fi, dp] @ w + b), max over k ----------------
template<int DIN, int DOUT>
__global__ __launch_bounds__(DOUT) void agg_kernel(
    const float* __restrict__ fin, const float* __restrict__ coords4,
    const int* __restrict__ knn_idx, const float* __restrict__ w,
    const float* __restrict__ bw, float* __restrict__ fout) {
  const int p = blockIdx.x;
  const int b = p >> 13;
  const int o = threadIdx.x;
  __shared__ float s_fi[DIN];
  __shared__ float s_nbT[DIN][K_];   // transposed: [d][k]
  __shared__ float s_np[K_][3];
  __shared__ int   s_idx[K_];

  if (o < K_) s_idx[o] = knn_idx[p*K_ + o];
  if (o < DIN) s_fi[o] = fin[p*DIN + o];      // DIN <= DOUT
  __syncthreads();

  for (int t = o; t < K_*DIN/4; t += DOUT) {
    const int k  = t & (K_-1);
    const int dq = t >> 4;
    const float4 v = *(const float4*)&fin[(((size_t)(b<<13) + s_idx[k]))*DIN + dq*4];
    s_nbT[dq*4+0][k] = v.x; s_nbT[dq*4+1][k] = v.y;
    s_nbT[dq*4+2][k] = v.z; s_nbT[dq*4+3][k] = v.w;
  }
  if (o < K_) {
    const float4 c = ((const float4*)coords4)[(b<<13) + s_idx[o]];
    s_np[o][0] = c.x; s_np[o][1] = c.y; s_np[o][2] = c.z;
  }
  __syncthreads();

  const float4 ci = ((const float4*)coords4)[p];
  const float wp0 = w[(2*DIN+0)*DOUT + o];
  const float wp1 = w[(2*DIN+1)*DOUT + o];
  const float wp2 = w[(2*DIN+2)*DOUT + o];

  // k-independent part: b + fi.(w_self - w_mid) - pi.w_pos
  float bpart = bw[o];
  for (int d = 0; d < DIN; ++d)
    bpart += s_fi[d] * (w[d*DOUT + o] - w[(DIN+d)*DOUT + o]);
  bpart -= ci.x*wp0 + ci.y*wp1 + ci.z*wp2;

  float acc[K_];
#pragma unroll
  for (int k = 0; k < K_; ++k)
    acc[k] = bpart + s_np[k][0]*wp0 + s_np[k][1]*wp1 + s_np[k][2]*wp2;

  for (int d = 0; d < DIN; ++d) {
    const float wv = w[(DIN+d)*DOUT + o];
    const float4 n0 = *(const float4*)&s_nbT[d][0];
    const float4 n1 = *(const float4*)&s_nbT[d][4];
    const float4 n2 = *(const float4*)&s_nbT[d][8];
    const float4 n3 = *(const float4*)&s_nbT[d][12];
    acc[0]  += n0.x*wv; acc[1]  += n0.y*wv; acc[2]  += n0.z*wv; acc[3]  += n0.w*wv;
    acc[4]  += n1.x*wv; acc[5]  += n1.y*wv; acc[6]  += n1.z*wv; acc[7]  += n1.w*wv;
    acc[8]  += n2.x*wv; acc[9]  += n2.y*wv; acc[10] += n2.z*wv; acc[11] += n2.w*wv;
    acc[12] += n3.x*wv; acc[13] += n3.y*wv; acc[14] += n3.z*wv; acc[15] += n3.w*wv;
  }
  float m = 0.f;   // relu outputs are >= 0, so max(relu) == max(0, accs)
#pragma unroll
  for (int k = 0; k < K_; ++k) m = fmaxf(m, acc[k]);
  fout[p*DOUT + o] = m;
}

// ---------------- global max (stage 1: partial over 256-point segments) ----------------
__global__ __launch_bounds__(256) void gmax_kernel(
    const float* __restrict__ f2, float* __restrict__ part) {
  const int b = blockIdx.x >> 5;       // /32
  const int seg = blockIdx.x & 31;
  const int o = threadIdx.x;
  float m = -INFINITY;
  const int n0 = seg * 256;
  for (int n = n0; n < n0 + 256; ++n)
    m = fmaxf(m, f2[((size_t)(b<<13) + n)*W2_ + o]);
  part[(size_t)blockIdx.x*W2_ + o] = m;
}

// ---------------- global max reduce + glob FC ----------------
__global__ __launch_bounds__(256) void gfc_kernel(
    const float* __restrict__ part, const float* __restrict__ gw,
    const float* __restrict__ gb, float* __restrict__ g2) {
  const int b = blockIdx.x;
  const int o = threadIdx.x;
  __shared__ float s_g[W2_];
  float m = -INFINITY;
  for (int s = 0; s < 32; ++s) m = fmaxf(m, part[(size_t)(b*32+s)*W2_ + o]);
  s_g[o] = m;
  __syncthreads();
  float acc = gb[o];
  for (int d = 0; d < W2_; ++d) acc += s_g[d]*gw[d*W2_ + o];
  g2[b*W2_ + o] = fmaxf(acc, 0.f);
}

// ---------------- head: relu([f2,g2] @ h1w + h1b) @ h2w + h2b + height bias ----------------
__global__ __launch_bounds__(256) void head_kernel(
    const float* __restrict__ f2, const float* __restrict__ g2,
    const float* __restrict__ h1w, const float* __restrict__ h1b,
    const float* __restrict__ h2w, const float* __restrict__ h2b,
    const float* __restrict__ x,
    const float* __restrict__ thresh, const float* __restrict__ sharp,
    const float* __restrict__ scale,
    float* __restrict__ out) {
  const int p0 = blockIdx.x * P_;
  const int b = p0 >> 13;
  const int o = threadIdx.x;
  __shared__ float s_in[512][P_];
  __shared__ float s_h[P_][W2_ + 1];

  for (int t = o; t < 256*P_; t += 256) {
    const int pp = t & (P_-1);
    const int d  = t >> 3;
    s_in[d][pp] = f2[(size_t)(p0+pp)*W2_ + d];
  }
  {
    const float gv = g2[b*W2_ + o];
#pragma unroll
    for (int pp = 0; pp < P_; ++pp) s_in[256 + o][pp] = gv;
  }
  __syncthreads();

  float acc[P_];
#pragma unroll
  for (int pp = 0; pp < P_; ++pp) acc[pp] = h1b[o];
  for (int d = 0; d < 512; ++d) {
    const float wv = h1w[d*256 + o];
    const float4 a = *(const float4*)&s_in[d][0];
    const float4 c = *(const float4*)&s_in[d][4];
    acc[0] += a.x*wv; acc[1] += a.y*wv; acc[2] += a.z*wv; acc[3] += a.w*wv;
    acc[4] += c.x*wv; acc[5] += c.y*wv; acc[6] += c.z*wv; acc[7] += c.w*wv;
  }
#pragma unroll
  for (int pp = 0; pp < P_; ++pp) s_h[pp][o] = fmaxf(acc[pp], 0.f);
  __syncthreads();

  if (o < P_*3) {
    const int pp = o / 3, c = o % 3;
    float s = h2b[c];
    for (int d = 0; d < 256; ++d) s += s_h[pp][d]*h2w[d*3 + c];
    if (c == 0) {
      const float hag = x[(size_t)(p0+pp)*4 + 3];
      const float t = sharp[0]*(thresh[0] - hag);
      s += scale[0] / (1.f + expf(-t));
    }
    out[(size_t)(p0+pp)*3 + c] = s;
  }
}

// ---------------- launch ----------------
extern "C" void kernel_launch(void* const* d_in, const int* in_sizes, int n_in,
                              void* d_out, int out_size, void* d_ws, size_t ws_size,
                              hipStream_t stream) {
  const float* x       = (const float*)d_in[0];
  const float* hmix_a  = (const float*)d_in[1];
  const float* hmix_b  = (const float*)d_in[2];
  const float* hmix_c  = (const float*)d_in[3];
  const float* stem_w  = (const float*)d_in[4];
  const float* stem_b  = (const float*)d_in[5];
  const float* b1_w    = (const float*)d_in[6];
  const float* b1_b    = (const float*)d_in[7];
  const float* b2_w    = (const float*)d_in[8];
  const float* b2_b    = (const float*)d_in[9];
  const float* glob_w  = (const float*)d_in[10];
  const float* glob_b  = (const float*)d_in[11];
  const float* head1_w = (const float*)d_in[12];
  const float* head1_b = (const float*)d_in[13];
  const float* head2_w = (const float*)d_in[14];
  const float* head2_b = (const float*)d_in[15];
  const float* thresh  = (const float*)d_in[16];
  const float* sharp   = (const float*)d_in[17];
  const float* scale   = (const float*)d_in[18];
  float* out = (float*)d_out;

  char* base = (char*)d_ws;
  float* coords4 = (float*)(base + 0);          //  4*8192*4 f = 512KB
  float* f0      = (float*)(base + 524288);     //  4*8192*64 f = 8MB
  int*   idxb    = (int*)  (base + 8912896);    //  4*8192*16 i = 2MB
  float* f1      = (float*)(base + 11010048);   //  4*8192*128 f = 16MB
  float* f2      = (float*)(base + 27787264);   //  4*8192*256 f = 32MB
  float* part    = (float*)(base + 61341696);   //  128*256 f = 128KB
  float* g2      = (float*)(base + 61472768);   //  4*256 f = 4KB

  const int NP = B_ * N_;   // 32768 points

  prep_kernel<<<NP, 64, 0, stream>>>(x, stem_w, stem_b, hmix_a, hmix_b, hmix_c,
                                     coords4, f0);
  knn_kernel<<<NP, 64, 0, stream>>>(coords4, idxb);
  agg_kernel<W0_, W1_><<<NP, W1_, 0, stream>>>(f0, coords4, idxb, b1_w, b1_b, f1);
  agg_kernel<W1_, W2_><<<NP, W2_, 0, stream>>>(f1, coords4, idxb, b2_w, b2_b, f2);
  gmax_kernel<<<B_*32, 256, 0, stream>>>(f2, part);
  gfc_kernel<<<B_, 256, 0, stream>>>(part, glob_w, glob_b, g2);
  head_kernel<<<NP / P_, 256, 0, stream>>>(f2, g2, head1_w, head1_b, head2_w, head2_b,
                                           x, thresh, sharp, scale, out);
}

// Round 2
// 1387.128 us; speedup vs baseline: 1.4854x; 1.4854x over previous
//
#include <hip/hip_runtime.h>
#include <math.h>

typedef unsigned long long u64;
typedef unsigned int u32;

#define B_ 4
#define N_ 8192
#define K_ 16
#define W0_ 64
#define W1_ 128
#define W2_ 256
#define P_ 8   // points per block in head kernel

// ---------------- prep: coords4 (x,y,z_eff,xx) + stem MLP ----------------
__global__ __launch_bounds__(64) void prep_kernel(
    const float* __restrict__ x,
    const float* __restrict__ stem_w, const float* __restrict__ stem_b,
    const float* __restrict__ hmix_a, const float* __restrict__ hmix_b,
    const float* __restrict__ hmix_c,
    float* __restrict__ coords4, float* __restrict__ f0) {
  const int p = blockIdx.x;          // global point 0..B*N-1
  const int o = threadIdx.x;         // 0..63
  const float x0 = x[p*4+0], x1 = x[p*4+1], x2 = x[p*4+2], x3 = x[p*4+3];
  float acc = stem_b[o];
  acc += x0*stem_w[0*W0_+o];
  acc += x1*stem_w[1*W0_+o];
  acc += x2*stem_w[2*W0_+o];
  acc += x3*stem_w[3*W0_+o];
  f0[p*W0_+o] = fmaxf(acc, 0.f);
  if (o == 0) {
    const float z  = hmix_a[0]*x2 + hmix_b[0]*x3 + hmix_c[0];
    const float xx = x0*x0 + x1*x1 + z*z;
    ((float4*)coords4)[p] = make_float4(x0, x1, z, xx);
  }
}

// ---------------- knn: one wave per 2 points ----------------
// Wave-distributed sorted top-16 (lane l<16 holds l-th best u64 key) +
// wave-uniform threshold filter: insertion only runs on ballot hits
// (~120 events/point instead of 8192 unconditional insertion sweeps).
__global__ __launch_bounds__(64) void knn_kernel(
    const float* __restrict__ coords4, int* __restrict__ knn_idx) {
  const int p0 = blockIdx.x * 2;
  const int p1 = p0 + 1;
  const int b = p0 >> 13;             // /8192 (pair never straddles a batch)
  const int lane = threadIdx.x;
  const float4* cb = ((const float4*)coords4) + (b << 13);
  const float4 c0 = ((const float4*)coords4)[p0];
  const float4 c1 = ((const float4*)coords4)[p1];

  u64 lk0 = ~0ull, lk1 = ~0ull;       // distributed list entry (lanes 0..15)
  u64 k15_0 = ~0ull, k15_1 = ~0ull;   // wave-uniform copy of worst kept key
  float T0 = INFINITY, T1 = INFINITY; // dist part of k15

  for (int it = 0; it < N_/64; ++it) {
    const int j = lane + it*64;
    const float4 cj = cb[j];
    float d0 = c0.w + cj.w - 2.f*(c0.x*cj.x + c0.y*cj.y + c0.z*cj.z);
    float d1 = c1.w + cj.w - 2.f*(c1.x*cj.x + c1.y*cj.y + c1.z*cj.z);
    d0 = fmaxf(d0, 0.f);
    d1 = fmaxf(d1, 0.f);

    u64 m0 = __ballot(d0 <= T0);      // ties pass; exact check inside
    while (m0) {
      const int s = (int)__ffsll((unsigned long long)m0) - 1;
      m0 &= m0 - 1;
      const float dc = __shfl(d0, s, 64);
      const u64 ck = ((u64)__float_as_uint(dc) << 32) | (u32)(s + it*64);
      if (ck < k15_0) {               // wave-uniform branch
        const bool cond = ck < lk0;
        const u64 pk = __shfl_up(lk0, 1, 64);
        const bool pc = (__shfl_up((int)cond, 1, 64) != 0) && (lane > 0);
        lk0 = cond ? (pc ? pk : ck) : lk0;
        k15_0 = __shfl(lk0, 15, 64);
        T0 = __uint_as_float((u32)(k15_0 >> 32));
      }
    }

    u64 m1 = __ballot(d1 <= T1);
    while (m1) {
      const int s = (int)__ffsll((unsigned long long)m1) - 1;
      m1 &= m1 - 1;
      const float dc = __shfl(d1, s, 64);
      const u64 ck = ((u64)__float_as_uint(dc) << 32) | (u32)(s + it*64);
      if (ck < k15_1) {
        const bool cond = ck < lk1;
        const u64 pk = __shfl_up(lk1, 1, 64);
        const bool pc = (__shfl_up((int)cond, 1, 64) != 0) && (lane > 0);
        lk1 = cond ? (pc ? pk : ck) : lk1;
        k15_1 = __shfl(lk1, 15, 64);
        T1 = __uint_as_float((u32)(k15_1 >> 32));
      }
    }
  }

  if (lane < K_) {                    // order irrelevant downstream (max-pool)
    knn_idx[p0*K_ + lane] = (int)(u32)(lk0 & 0xffffffffull);
    knn_idx[p1*K_ + lane] = (int)(u32)(lk1 & 0xffffffffull);
  }
}

// ---------------- local_agg: relu(concat[fi, nb-fi, dp] @ w + b), max over k ----------------
template<int DIN, int DOUT>
__global__ __launch_bounds__(DOUT) void agg_kernel(
    const float* __restrict__ fin, const float* __restrict__ coords4,
    const int* __restrict__ knn_idx, const float* __restrict__ w,
    const float* __restrict__ bw, float* __restrict__ fout) {
  const int p = blockIdx.x;
  const int b = p >> 13;
  const int o = threadIdx.x;
  __shared__ float s_fi[DIN];
  __shared__ float s_nbT[DIN][K_];   // transposed: [d][k]
  __shared__ float s_np[K_][3];
  __shared__ int   s_idx[K_];

  if (o < K_) s_idx[o] = knn_idx[p*K_ + o];
  if (o < DIN) s_fi[o] = fin[p*DIN + o];      // DIN <= DOUT
  __syncthreads();

  for (int t = o; t < K_*DIN/4; t += DOUT) {
    const int k  = t & (K_-1);
    const int dq = t >> 4;
    const float4 v = *(const float4*)&fin[(((size_t)(b<<13) + s_idx[k]))*DIN + dq*4];
    s_nbT[dq*4+0][k] = v.x; s_nbT[dq*4+1][k] = v.y;
    s_nbT[dq*4+2][k] = v.z; s_nbT[dq*4+3][k] = v.w;
  }
  if (o < K_) {
    const float4 c = ((const float4*)coords4)[(b<<13) + s_idx[o]];
    s_np[o][0] = c.x; s_np[o][1] = c.y; s_np[o][2] = c.z;
  }
  __syncthreads();

  const float4 ci = ((const float4*)coords4)[p];
  const float wp0 = w[(2*DIN+0)*DOUT + o];
  const float wp1 = w[(2*DIN+1)*DOUT + o];
  const float wp2 = w[(2*DIN+2)*DOUT + o];

  // k-independent part: b + fi.(w_self - w_mid) - pi.w_pos
  float bpart = bw[o];
  for (int d = 0; d < DIN; ++d)
    bpart += s_fi[d] * (w[d*DOUT + o] - w[(DIN+d)*DOUT + o]);
  bpart -= ci.x*wp0 + ci.y*wp1 + ci.z*wp2;

  float acc[K_];
#pragma unroll
  for (int k = 0; k < K_; ++k)
    acc[k] = bpart + s_np[k][0]*wp0 + s_np[k][1]*wp1 + s_np[k][2]*wp2;

  for (int d = 0; d < DIN; ++d) {
    const float wv = w[(DIN+d)*DOUT + o];
    const float4 n0 = *(const float4*)&s_nbT[d][0];
    const float4 n1 = *(const float4*)&s_nbT[d][4];
    const float4 n2 = *(const float4*)&s_nbT[d][8];
    const float4 n3 = *(const float4*)&s_nbT[d][12];
    acc[0]  += n0.x*wv; acc[1]  += n0.y*wv; acc[2]  += n0.z*wv; acc[3]  += n0.w*wv;
    acc[4]  += n1.x*wv; acc[5]  += n1.y*wv; acc[6]  += n1.z*wv; acc[7]  += n1.w*wv;
    acc[8]  += n2.x*wv; acc[9]  += n2.y*wv; acc[10] += n2.z*wv; acc[11] += n2.w*wv;
    acc[12] += n3.x*wv; acc[13] += n3.y*wv; acc[14] += n3.z*wv; acc[15] += n3.w*wv;
  }
  float m = 0.f;   // relu outputs are >= 0, so max(relu) == max(0, accs)
#pragma unroll
  for (int k = 0; k < K_; ++k) m = fmaxf(m, acc[k]);
  fout[p*DOUT + o] = m;
}

// ---------------- global max (stage 1: partial over 256-point segments) ----------------
__global__ __launch_bounds__(256) void gmax_kernel(
    const float* __restrict__ f2, float* __restrict__ part) {
  const int b = blockIdx.x >> 5;       // /32
  const int seg = blockIdx.x & 31;
  const int o = threadIdx.x;
  float m = -INFINITY;
  const int n0 = seg * 256;
  for (int n = n0; n < n0 + 256; ++n)
    m = fmaxf(m, f2[((size_t)(b<<13) + n)*W2_ + o]);
  part[(size_t)blockIdx.x*W2_ + o] = m;
}

// ---------------- global max reduce + glob FC ----------------
__global__ __launch_bounds__(256) void gfc_kernel(
    const float* __restrict__ part, const float* __restrict__ gw,
    const float* __restrict__ gb, float* __restrict__ g2) {
  const int b = blockIdx.x;
  const int o = threadIdx.x;
  __shared__ float s_g[W2_];
  float m = -INFINITY;
  for (int s = 0; s < 32; ++s) m = fmaxf(m, part[(size_t)(b*32+s)*W2_ + o]);
  s_g[o] = m;
  __syncthreads();
  float acc = gb[o];
  for (int d = 0; d < W2_; ++d) acc += s_g[d]*gw[d*W2_ + o];
  g2[b*W2_ + o] = fmaxf(acc, 0.f);
}

// ---------------- head: relu([f2,g2] @ h1w + h1b) @ h2w + h2b + height bias ----------------
__global__ __launch_bounds__(256) void head_kernel(
    const float* __restrict__ f2, const float* __restrict__ g2,
    const float* __restrict__ h1w, const float* __restrict__ h1b,
    const float* __restrict__ h2w, const float* __restrict__ h2b,
    const float* __restrict__ x,
    const float* __restrict__ thresh, const float* __restrict__ sharp,
    const float* __restrict__ scale,
    float* __restrict__ out) {
  const int p0 = blockIdx.x * P_;
  const int b = p0 >> 13;
  const int o = threadIdx.x;
  __shared__ float s_in[512][P_];
  __shared__ float s_h[P_][W2_ + 1];

  for (int t = o; t < 256*P_; t += 256) {
    const int pp = t & (P_-1);
    const int d  = t >> 3;
    s_in[d][pp] = f2[(size_t)(p0+pp)*W2_ + d];
  }
  {
    const float gv = g2[b*W2_ + o];
#pragma unroll
    for (int pp = 0; pp < P_; ++pp) s_in[256 + o][pp] = gv;
  }
  __syncthreads();

  float acc[P_];
#pragma unroll
  for (int pp = 0; pp < P_; ++pp) acc[pp] = h1b[o];
  for (int d = 0; d < 512; ++d) {
    const float wv = h1w[d*256 + o];
    const float4 a = *(const float4*)&s_in[d][0];
    const float4 c = *(const float4*)&s_in[d][4];
    acc[0] += a.x*wv; acc[1] += a.y*wv; acc[2] += a.z*wv; acc[3] += a.w*wv;
    acc[4] += c.x*wv; acc[5] += c.y*wv; acc[6] += c.z*wv; acc[7] += c.w*wv;
  }
#pragma unroll
  for (int pp = 0; pp < P_; ++pp) s_h[pp][o] = fmaxf(acc[pp], 0.f);
  __syncthreads();

  if (o < P_*3) {
    const int pp = o / 3, c = o % 3;
    float s = h2b[c];
    for (int d = 0; d < 256; ++d) s += s_h[pp][d]*h2w[d*3 + c];
    if (c == 0) {
      const float hag = x[(size_t)(p0+pp)*4 + 3];
      const float t = sharp[0]*(thresh[0] - hag);
      s += scale[0] / (1.f + expf(-t));
    }
    out[(size_t)(p0+pp)*3 + c] = s;
  }
}

// ---------------- launch ----------------
extern "C" void kernel_launch(void* const* d_in, const int* in_sizes, int n_in,
                              void* d_out, int out_size, void* d_ws, size_t ws_size,
                              hipStream_t stream) {
  const float* x       = (const float*)d_in[0];
  const float* hmix_a  = (const float*)d_in[1];
  const float* hmix_b  = (const float*)d_in[2];
  const float* hmix_c  = (const float*)d_in[3];
  const float* stem_w  = (const float*)d_in[4];
  const float* stem_b  = (const float*)d_in[5];
  const float* b1_w    = (const float*)d_in[6];
  const float* b1_b    = (const float*)d_in[7];
  const float* b2_w    = (const float*)d_in[8];
  const float* b2_b    = (const float*)d_in[9];
  const float* glob_w  = (const float*)d_in[10];
  const float* glob_b  = (const float*)d_in[11];
  const float* head1_w = (const float*)d_in[12];
  const float* head1_b = (const float*)d_in[13];
  const float* head2_w = (const float*)d_in[14];
  const float* head2_b = (const float*)d_in[15];
  const float* thresh  = (const float*)d_in[16];
  const float* sharp   = (const float*)d_in[17];
  const float* scale   = (const float*)d_in[18];
  float* out = (float*)d_out;

  char* base = (char*)d_ws;
  float* coords4 = (float*)(base + 0);          //  4*8192*4 f = 512KB
  float* f0      = (float*)(base + 524288);     //  4*8192*64 f = 8MB
  int*   idxb    = (int*)  (base + 8912896);    //  4*8192*16 i = 2MB
  float* f1      = (float*)(base + 11010048);   //  4*8192*128 f = 16MB
  float* f2      = (float*)(base + 27787264);   //  4*8192*256 f = 32MB
  float* part    = (float*)(base + 61341696);   //  128*256 f = 128KB
  float* g2      = (float*)(base + 61472768);   //  4*256 f = 4KB

  const int NP = B_ * N_;   // 32768 points

  prep_kernel<<<NP, 64, 0, stream>>>(x, stem_w, stem_b, hmix_a, hmix_b, hmix_c,
                                     coords4, f0);
  knn_kernel<<<NP / 2, 64, 0, stream>>>(coords4, idxb);
  agg_kernel<W0_, W1_><<<NP, W1_, 0, stream>>>(f0, coords4, idxb, b1_w, b1_b, f1);
  agg_kernel<W1_, W2_><<<NP, W2_, 0, stream>>>(f1, coords4, idxb, b2_w, b2_b, f2);
  gmax_kernel<<<B_*32, 256, 0, stream>>>(f2, part);
  gfc_kernel<<<B_, 256, 0, stream>>>(part, glob_w, glob_b, g2);
  head_kernel<<<NP / P_, 256, 0, stream>>>(f2, g2, head1_w, head1_b, head2_w, head2_b,
                                           x, thresh, sharp, scale, out);
}